// Round 5
// baseline (78.183 us; speedup 1.0000x reference)
//
#include <hip/hip_runtime.h>
#include <hip/hip_fp16.h>

// SoftNCutsLoss on MI355X — R18.
// batch: (4,1,32,32,32) f32, preds: (4,8,32,32,32) f32 -> out: (4,) f32
//
// R18 = w-pair DS sharing (R14's idea) rebuilt on R17's rolled/__constant__
// machinery. Decomposition from R14's broken round: fixed non-main cost
// ~55.2us (fill 41 + finalize/launches/memsets ~14) => main ~22.5us now.
// R16 (2x waves neutral) => pinned on a per-CU shared pipe; DS is the only
// per-CU pipe in the model (~7.4-12us incl. waits). So: cut total DS 41%.
//  - Each thread owns a w-adjacent voxel PAIR (w,w+1). Union of the two
//    lex-positive half-balls (H and H+z^) = 148 slots for 250 interactions:
//    each b32+b128 LDS read serves up to 2 voxels; f16->f32 cvts shared.
//  - ROLLED loop over __constant__ CPTAB[4][40] {off,lw0,lw1,pad}: invalid
//    side has lw=-1e4 -> exp2 -> 0.0 exactly -> branchless. No unroll-budget
//    blowup (R14's scratch catastrophe came from a function-local constexpr
//    table + oversized unrolled body; R17 proved the rolled __constant__ form
//    emits s_loads, no scratch).
//  - 4 classes x 40 entries (round-robin split of the 148), cid=tid>>7
//    wave-uniform; 128 pairs x 4 classes = 512 threads.
//  - q0/q1 loaded AFTER the loop (R16 lesson, keeps loop live-set small).
// Staging, LDS-transpose epilogue, S-table, finalize: R15/R17-proven, unchanged.
// DS-op pairs per block: 256x125=32000 -> 128x148=18944 (-41%).

#define EPS_F 2.220446049250313e-16f

constexpr int TD = 4, TH = 8, TW = 8;      // tile dims (d,h,w)
constexpr int HDh = 7, HHh = 14, HWh = 14; // halo: x forward-only +3, y/z +-3
constexpr int SYB = 17;                    // halo h-stride
constexpr int SXB = HHh * SYB;             // 238, halo d-stride
constexpr int NB  = 6 * SXB + 13 * SYB + 13 + 1;  // 1663 voxel slots
constexpr int NT = 512;                    // threads per block (8 waves)
constexpr int NBLK = 512;                  // 4 batches * 128 tiles
constexpr int NTASK = HDh * HHh * 4;       // 392 staging tasks (row x 4 chunks)

// exponent folding: aff = exp2(d2*K1 + c2*K2)
#define K1F (-0.014426950408889634f)       // -0.01 * log2(e)
#define K2F (-0.09016844005556021f)        // -log2(e)/16
#define LW_DEAD (-10000.0f)                // exp2(-1e4) == 0.0f exactly

constexpr bool inH(int x, int y, int z) {
    if (x < 0 || x > 3 || y < -3 || y > 3 || z < -3 || z > 3) return false;
    const int c2 = x * x + y * y + z * z;
    if (c2 == 0 || c2 >= 16) return false;
    if (x == 0 && (y < 0 || (y == 0 && z <= 0))) return false;
    return true;
}

struct PEnt { int off; float lw0; float lw1; float pad; };  // 16B -> s_load_dwordx4
struct CPTab { PEnt e[4][40]; };

constexpr CPTab make_cptab() {
    CPTab c{};
    int cnt[4] = {0, 0, 0, 0};
    int idx = 0;
    for (int x = 0; x <= 3; ++x)
        for (int y = -3; y <= 3; ++y)
            for (int z = -3; z <= 4; ++z) {          // z to +4: H shifted by +z^
                const bool v0 = inH(x, y, z);        // serves voxel0 with h=(x,y,z)
                const bool v1 = inH(x, y, z - 1);    // serves voxel1 with h=(x,y,z-1)
                if (!v0 && !v1) continue;
                const int cls = idx & 3; ++idx;      // 148 total -> 37 per class
                PEnt& p = c.e[cls][cnt[cls]++];
                p.off = x * SXB + y * SYB + z;       // always >= 1 (positive lex)
                p.lw0 = v0 ? (float)(x * x + y * y + z * z) * K2F : LW_DEAD;
                p.lw1 = v1 ? (float)(x * x + y * y + (z - 1) * (z - 1)) * K2F : LW_DEAD;
                p.pad = 0.f;
            }
    for (int cls = 0; cls < 4; ++cls)                // pad to 40 with dead entries
        for (int i = cnt[cls]; i < 40; ++i) {
            c.e[cls][i].off = 0;                     // own voxel: always-valid read
            c.e[cls][i].lw0 = LW_DEAD;
            c.e[cls][i].lw1 = LW_DEAD;
            c.e[cls][i].pad = 0.f;
        }
    return c;
}
__constant__ CPTab CPTAB = make_cptab();

// ---------- constexpr border-S table: S(class_d, class_h, class_w) ----------
constexpr float W16[16] = {
    1.0f,                    0.93941306281347578611f, 0.88249690258459546286f,
    0.82902911818040034301f, 0.77880078307140486825f, 0.73161562894664190813f,
    0.68728927879097219970f, 0.64565423513106973593f, 0.60653065971263342360f,
    0.56978282473092302544f, 0.53526142851899028012f, 0.50283157797094090696f,
    0.47236655274101470713f, 0.44374731008100323837f, 0.41686201967850837523f,
    0.39160740400665634335f };

struct STab { float s[343]; };
constexpr STab make_stab() {
    STab t{};
    for (int a = 0; a < 7; ++a)
        for (int b = 0; b < 7; ++b)
            for (int c = 0; c < 7; ++c) {
                const int pa = a < 3 ? a : (a == 3 ? 16 : a + 25);
                const int pb = b < 3 ? b : (b == 3 ? 16 : b + 25);
                const int pc = c < 3 ? c : (c == 3 ? 16 : c + 25);
                float s = 0.f;
                for (int dx = -3; dx <= 3; ++dx)
                    for (int dy = -3; dy <= 3; ++dy)
                        for (int dz = -3; dz <= 3; ++dz) {
                            const int c2 = dx * dx + dy * dy + dz * dz;
                            if (c2 >= 16) continue;
                            const bool neg = (dx < 0) ||
                                (dx == 0 && (dy < 0 || (dy == 0 && dz < 0)));
                            if (!neg) continue;
                            const bool in = (pa + dx) >= 0 && (pa + dx) < 32 &&
                                            (pb + dy) >= 0 && (pb + dy) < 32 &&
                                            (pc + dz) >= 0 && (pc + dz) < 32;
                            if (!in) s += W16[c2];
                        }
                t.s[(a * 7 + b) * 7 + c] = s;
            }
    return t;
}
__constant__ STab STAB = make_stab();

__device__ __forceinline__ int bcls(int p) {
    return p < 3 ? p : (p > 28 ? p - 25 : 3);
}

__device__ __forceinline__ unsigned pack2(float a, float b) {
    return (unsigned)__half_as_ushort(__float2half(a)) |
           ((unsigned)__half_as_ushort(__float2half(b)) << 16);
}

// Rolled pair-accumulate: 40 entries, batch 4. Table reads are wave-uniform
// scalar loads; DS reads shared by both voxels of the pair; dead sides give
// aff == 0.0 exactly (exp2 underflow), so fmas are no-ops numerically.
__device__ __forceinline__ void accum_pair_rolled(const float* __restrict__ sB,
                                                  const uint4* __restrict__ sPk,
                                                  int vown, float b0, float b1,
                                                  const PEnt* __restrict__ tab,
                                                  float a0[9], float a1[9]) {
#pragma clang loop unroll_count(2)
    for (int i = 0; i < 40; i += 4) {
        float sb[4];
        uint4 pk[4];
        float l0[4], l1[4];
#pragma unroll
        for (int j = 0; j < 4; ++j) {
            const int off = tab[i + j].off;          // s_load_dwordx4 (uniform)
            l0[j] = tab[i + j].lw0;
            l1[j] = tab[i + j].lw1;
            const int nv = vown + off;
            sb[j] = sB[nv];
            pk[j] = sPk[nv];
        }
#pragma unroll
        for (int j = 0; j < 4; ++j) {
            __half2 h[4];
            __builtin_memcpy(h, &pk[j], 16);
            float pf[8];
            pf[0] = __half2float(__low2half(h[0]));  pf[1] = __half2float(__high2half(h[0]));
            pf[2] = __half2float(__low2half(h[1]));  pf[3] = __half2float(__high2half(h[1]));
            pf[4] = __half2float(__low2half(h[2]));  pf[5] = __half2float(__high2half(h[2]));
            pf[6] = __half2float(__low2half(h[3]));  pf[7] = __half2float(__high2half(h[3]));
            const float d0 = b0 - sb[j];
            const float aff0 =
                __builtin_amdgcn_exp2f(__builtin_fmaf(d0 * d0, K1F, l0[j]));
            a0[8] += aff0;
#pragma unroll
            for (int k = 0; k < 8; ++k) a0[k] = __builtin_fmaf(aff0, pf[k], a0[k]);
            const float d1 = b1 - sb[j];
            const float aff1 =
                __builtin_amdgcn_exp2f(__builtin_fmaf(d1 * d1, K1F, l1[j]));
            a1[8] += aff1;
#pragma unroll
            for (int k = 0; k < 8; ++k) a1[k] = __builtin_fmaf(aff1, pf[k], a1[k]);
        }
    }
}

__global__ __launch_bounds__(NT, 4)
void softncuts_main(const float* __restrict__ batch,
                    const float* __restrict__ preds,
                    float* __restrict__ partials) {
    __shared__ float sB[NB];            // batch halo, f32 (6.5 KB)
    __shared__ uint4 sPk[NB];           // preds halo, 8 x f16 packed (26 KB)
    __shared__ float valsT[NT * 20];    // epilogue transpose, row stride 20 (40 KB)

    const int bid  = blockIdx.x;
    const int bb   = bid >> 7;          // batch index 0..3
    const int tile = bid & 127;
    const int tw = tile & 3;            // -> w0 = tw*8
    const int th = (tile >> 2) & 3;     // -> h0 = th*8
    const int td = tile >> 4;           // -> d0 = td*4
    const int d0 = td * TD, h0 = th * TH, w0 = tw * TW;

    const int tid  = threadIdx.x;

    const float* bbase = batch + (size_t)bb * 32768;
    const float* pbase = preds + (size_t)bb * 8 * 32768;

    // ---- stage forward-x halo, float4-vectorized along w (proven path) ----
    if (tid < NTASK) {
        const int t   = tid;
        const int c   = t & 3;
        const int row = t >> 2;
        const int hh  = row % HHh;
        const int hd  = row / HHh;
        const int gd  = d0 + hd;
        const int gh  = h0 + hh - 3;
        const int gw0 = w0 - 4 + c * 4;
        const int hwb = c * 4 - 1;
        const bool fast = (gd < 32) & ((unsigned)gh < 32u) & (gw0 >= 0) & (gw0 + 3 < 32);
        if (fast) {
            const int sidx = (gd * 32 + gh) * 32 + gw0;   // 16B-aligned
            float4 pv[9];
            pv[0] = *(const float4*)(bbase + sidx);
#pragma unroll
            for (int k = 0; k < 8; ++k)
                pv[k + 1] = *(const float4*)(pbase + sidx + k * 32768);
#pragma unroll
            for (int e = 0; e < 4; ++e) {
                const int hw = hwb + e;
                if (hw < 0 || hw >= HWh) continue;
                const int f = hd * SXB + hh * SYB + hw;
                sB[f] = ((const float*)&pv[0])[e];
                unsigned u[4];
#pragma unroll
                for (int k = 0; k < 4; ++k)
                    u[k] = pack2(((const float*)&pv[2 * k + 1])[e],
                                 ((const float*)&pv[2 * k + 2])[e]);
                sPk[f] = make_uint4(u[0], u[1], u[2], u[3]);
            }
        } else {
#pragma unroll
            for (int e = 0; e < 4; ++e) {
                const int hw = hwb + e;
                if (hw < 0 || hw >= HWh) continue;
                const int gw = gw0 + e;
                const bool in = (gd < 32) & ((unsigned)gh < 32u) & ((unsigned)gw < 32u);
                const int sidx = (gd * 32 + gh) * 32 + gw;
                const int f = hd * SXB + hh * SYB + hw;
                sB[f] = in ? bbase[sidx] : EPS_F;
                unsigned u[4];
#pragma unroll
                for (int k = 0; k < 4; ++k)
                    u[k] = pack2(in ? pbase[sidx + (2 * k) * 32768]     : 0.f,
                                 in ? pbase[sidx + (2 * k + 1) * 32768] : 0.f);
                sPk[f] = make_uint4(u[0], u[1], u[2], u[3]);
            }
        }
    }
    __syncthreads();

    // ---- thread -> (voxel pair, table class) ----
    const int cid  = tid >> 7;          // 0..3, wave-uniform (2 waves/class)
    const int vtid = tid & 127;         // pair id: 4 (w-pairs) x 8 (h) x 4 (d)
    const int lwp = vtid & 3;           // own w = {lwp*2, lwp*2+1}
    const int lh  = (vtid >> 2) & 7;
    const int ld  = vtid >> 5;

    const int gdo = d0 + ld, gho = h0 + lh, gw0v = w0 + lwp * 2;
    const int sidx0 = (gdo * 32 + gho) * 32 + gw0v;   // even -> float2 aligned
    const float2 bv = *(const float2*)(bbase + sidx0);
    const float b0 = bv.x, b1 = bv.y;

    const int vown = ld * SXB + (lh + 3) * SYB + (lwp * 2 + 3);

    float a0[9], a1[9];
#pragma unroll
    for (int i = 0; i < 9; ++i) { a0[i] = 0.f; a1[i] = 0.f; }

    const int cidu = __builtin_amdgcn_readfirstlane(cid);
    accum_pair_rolled(sB, sPk, vown, b0, b1, CPTAB.e[cidu], a0, a1);

    // ---- own preds loaded AFTER the loop (keeps loop live-set small) ----
    float q0[8], q1[8];
#pragma unroll
    for (int k = 0; k < 8; ++k) {
        const float2 qv = *(const float2*)(pbase + sidx0 + k * 32768);
        q0[k] = qv.x; q1[k] = qv.y;
    }

    // ---- self + pad terms exactly once per voxel (class 0 only) ----
    float sp0 = 0.f, sp1 = 0.f;
    if (cid == 0) {
        const int base = (bcls(gdo) * 7 + bcls(gho)) * 7;
        const float S0 = STAB.s[base + bcls(gw0v)];
        const float S1 = STAB.s[base + bcls(gw0v + 1)];
        const float db0 = b0 - EPS_F, db1 = b1 - EPS_F;
        sp0 = 1.f + S0 * __expf(db0 * db0 * -0.01f);
        sp1 = 1.f + S1 * __expf(db1 * db1 * -0.01f);
    }

    float vals[16];
#pragma unroll
    for (int k = 0; k < 8; ++k) {
        const float s0 = (cid == 0) ? q0[k] : 0.f;
        const float s1 = (cid == 0) ? q1[k] : 0.f;
        vals[k]     = q0[k] * (2.f * a0[k] + s0) + q1[k] * (2.f * a1[k] + s1);
        vals[8 + k] = q0[k] * (a0[8] + sp0) + a0[k]
                    + q1[k] * (a1[8] + sp1) + a1[k];
    }

    // ---- LDS-transpose block reduction (R15-proven) ----
    {
        float* vr = &valsT[tid * 20];                 // 80 B rows, 16B aligned
        ((float4*)vr)[0] = make_float4(vals[0],  vals[1],  vals[2],  vals[3]);
        ((float4*)vr)[1] = make_float4(vals[4],  vals[5],  vals[6],  vals[7]);
        ((float4*)vr)[2] = make_float4(vals[8],  vals[9],  vals[10], vals[11]);
        ((float4*)vr)[3] = make_float4(vals[12], vals[13], vals[14], vals[15]);
    }
    __syncthreads();
    {
        const int val = tid >> 5;                     // 0..15
        const int r   = tid & 31;                     // 32 readers per value
        float s = 0.f;
#pragma unroll
        for (int k = 0; k < 16; ++k)
            s += valsT[(r + 32 * k) * 20 + val];
        for (int off = 16; off; off >>= 1) s += __shfl_down(s, off, 32);
        if (r == 0) partials[val * NBLK + bid] = s;
    }
}

__global__ __launch_bounds__(1024)
void softncuts_finalize(const float* __restrict__ partials,
                        float* __restrict__ out) {
    __shared__ float red[64];
    const int tid = threadIdx.x;          // 0..1023
    const int group = tid >> 4;           // 0..63 = bb*16 + slot
    const int j0 = tid & 15;
    const int slot = group & 15;
    const int bb = group >> 4;

    const float* p = partials + slot * NBLK + bb * 128;   // 128 tiles per batch
    float s = 0.f;
#pragma unroll
    for (int k = 0; k < 8; ++k) s += p[j0 + 16 * k];
    for (int off = 8; off; off >>= 1) s += __shfl_down(s, off, 16);
    if (j0 == 0) red[group] = s;
    __syncthreads();

    if (tid < 4) {
        float accv = 0.f;
#pragma unroll
        for (int k = 0; k < 8; ++k)
            accv += red[tid * 16 + k] / red[tid * 16 + 8 + k];
        out[tid] = 8.0f - accv;
    }
}

extern "C" void kernel_launch(void* const* d_in, const int* in_sizes, int n_in,
                              void* d_out, int out_size, void* d_ws, size_t ws_size,
                              hipStream_t stream) {
    const float* batch = (const float*)d_in[0];
    const float* preds = (const float*)d_in[1];
    float* out      = (float*)d_out;
    float* partials = (float*)d_ws;   // 16*NBLK floats = 32 KB

    softncuts_main<<<dim3(NBLK), dim3(NT), 0, stream>>>(batch, preds, partials);
    softncuts_finalize<<<dim3(1), dim3(1024), 0, stream>>>(partials, out);
}